// Round 9
// baseline (435.119 us; speedup 1.0000x reference)
//
#include <hip/hip_runtime.h>
#include <hip/hip_fp16.h>

#define NCH 128

typedef short bf16x8 __attribute__((ext_vector_type(8)));
typedef float f32x4 __attribute__((ext_vector_type(4)));

__device__ __forceinline__ unsigned short f32_to_bf16_rne(float f) {
    unsigned u = __float_as_uint(f);
    unsigned r = u + 0x7FFFu + ((u >> 16) & 1u);
    return (unsigned short)(r >> 16);
}
// trunc-split: hi = trunc16(f), lo = rne(f - hi). |lo| <= 2^-8|f|.
__device__ __forceinline__ void split_bf16(float f, unsigned short& hi, unsigned short& lo) {
    unsigned u = __float_as_uint(f);
    hi = (unsigned short)(u >> 16);
    float l = f - __uint_as_float(u & 0xFFFF0000u);
    lo = f32_to_bf16_rne(l);
}

// ---------------- CSR build ----------------
// After deg+scan: off[d] = start of node d. fill bumps off[d]; after: off[d] = inclusive end.

__global__ void gin_deg_kernel(const int* __restrict__ dst, int* __restrict__ off, int E) {
    int e = blockIdx.x * 256 + threadIdx.x;
    if (e < E) atomicAdd(&off[dst[e] + 1], 1);
}

__global__ void gin_scan1(const int* __restrict__ off, int* __restrict__ part, int n) {
    __shared__ int red[256];
    int t = threadIdx.x;
    int base = blockIdx.x * 2048 + t * 8;
    int s = 0;
    if (base + 8 <= n) {
        #pragma unroll
        for (int i = 0; i < 8; ++i) s += off[base + i];
    } else {
        for (int i = 0; i < 8; ++i) { int idx = base + i; if (idx < n) s += off[idx]; }
    }
    red[t] = s;
    __syncthreads();
    #pragma unroll
    for (int o = 128; o > 0; o >>= 1) {
        if (t < o) red[t] += red[t + o];
        __syncthreads();
    }
    if (t == 0) part[blockIdx.x] = red[0];
}

__global__ void gin_scan2(int* __restrict__ part, int nb) {
    __shared__ int sh[256];
    int t = threadIdx.x;
    int v = (t < nb) ? part[t] : 0;
    sh[t] = v;
    __syncthreads();
    #pragma unroll
    for (int o = 1; o < 256; o <<= 1) {
        int u = (t >= o) ? sh[t - o] : 0;
        __syncthreads();
        sh[t] += u;
        __syncthreads();
    }
    if (t < nb) part[t] = sh[t] - v;
}

__global__ void gin_scan3(int* __restrict__ off, const int* __restrict__ part, int n) {
    __shared__ int red[256];
    int t = threadIdx.x;
    int base = blockIdx.x * 2048 + t * 8;
    int loc[8];
    int s = 0;
    #pragma unroll
    for (int i = 0; i < 8; ++i) {
        int idx = base + i;
        int v = (idx < n) ? off[idx] : 0;
        s += v;
        loc[i] = s;
    }
    red[t] = s;
    __syncthreads();
    #pragma unroll
    for (int o = 1; o < 256; o <<= 1) {
        int u = (t >= o) ? red[t - o] : 0;
        __syncthreads();
        red[t] += u;
        __syncthreads();
    }
    int offset = part[blockIdx.x] + red[t] - s;
    #pragma unroll
    for (int i = 0; i < 8; ++i) {
        int idx = base + i;
        if (idx < n) off[idx] = loc[i] + offset;
    }
}

__global__ void gin_fill_kernel(const int* __restrict__ src, const int* __restrict__ dst,
                                int* __restrict__ off, int* __restrict__ csr, int E) {
    int e = blockIdx.x * 256 + threadIdx.x;
    if (e < E) {
        int d = dst[e];
        int p = atomicAdd(&off[d], 1);
        csr[p] = src[e];
    }
}

// ---------------- x -> fp16 ----------------
__global__ void gin_f2h_kernel(const float* __restrict__ x, __half* __restrict__ xh, int n4) {
    int i = blockIdx.x * 256 + threadIdx.x;
    if (i >= n4) return;
    float4 v = ((const float4*)x)[i];
    union { __half h[4]; uint2 u; } o;
    o.h[0] = __float2half(v.x); o.h[1] = __float2half(v.y);
    o.h[2] = __float2half(v.z); o.h[3] = __float2half(v.w);
    ((uint2*)xh)[i] = o.u;
}

// ---------------- weight pre-pack into MFMA B-fragment order (bf16 hi/lo) ----------------
__global__ void gin_pack_kernel(const float* __restrict__ W, int K, int N,
                                unsigned short* __restrict__ out) {
    int idx = blockIdx.x * 256 + threadIdx.x;
    int KC = K / 32, NT = N / 16;
    int total = 2 * KC * NT * 64 * 8;
    if (idx >= total) return;
    int j = idx & 7;
    int l = (idx >> 3) & 63;
    int v = idx >> 9;
    int nt = v % NT; v /= NT;
    int kc = v % KC;
    int spl = v / KC;
    int k = kc * 32 + (l >> 4) * 8 + j;
    int n = nt * 16 + (l & 15);
    float w = W[(size_t)k * N + n];
    unsigned short hi, lo;
    split_bf16(w, hi, lo);
    out[idx] = (spl == 0) ? hi : lo;
}

// ---------------- fused GINConv layer: register gather + LDS-staged-weight MLP ----------------
// 256 threads = 4 waves, 16 nodes/wave, 64 nodes/block.
// Weights staged in one 64KB LDS buffer shared by all waves: W1(hi+lo) for GEMM1,
// re-staged with W2(hi+lo) for GEMM2 (3 barriers total). B-frag reads become
// ds_read_b128 (~12cyc) instead of per-wave L2 streams (~250cyc, 800MB/dispatch).
// Gather is register-direct (round-8); GEMM1->GEMM2 via wave-private scratch.
template <int N1, int N2, typename OutT>
__global__ __launch_bounds__(256)
void gin_fused(const __half* __restrict__ Hin, const int* __restrict__ offend,
               const int* __restrict__ csr, const float* __restrict__ eps_p, int layer,
               const unsigned short* __restrict__ PW1, const float* __restrict__ B1,
               const unsigned short* __restrict__ PW2, const float* __restrict__ B2,
               OutT* __restrict__ Out, int nrows) {
    constexpr int K1 = 128;
    constexpr int KC1 = K1 / 32, NT1 = N1 / 16, KC2 = N1 / 32, NT2 = N2 / 16;
    constexpr int SW1 = 2 * KC1 * NT1 * 512;   // shorts: hi+lo packed W1
    constexpr int SW2 = 2 * KC2 * NT2 * 512;   // shorts: hi+lo packed W2
    constexpr int SS = 36;                     // scratch f32 row stride
    __shared__ __align__(16) unsigned short Wlds[32768];  // 64KB, max(SW1,SW2)
    __shared__ __align__(16) float Scr[4 * 16 * SS];

    const int tid = threadIdx.x;
    const int w = tid >> 6;
    const int l = tid & 63;
    const int lr = l & 15;   // node/row within wave band; A-row / B-col / C-col
    const int lg = l >> 4;   // k-group; A-k = kc*32+lg*8+j; C-row = lg*4+r
    const int m0 = blockIdx.x * 64 + w * 16;
    const int node = m0 + lr;
    float* sw = &Scr[w * 16 * SS];

    // ---- stage W1 (hi+lo) into LDS (coalesced uint4 stream) ----
    #pragma unroll
    for (int i = 0; i < SW1 / 2048; ++i) {
        int o = i * 2048 + tid * 8;
        *(uint4*)&Wlds[o] = *(const uint4*)&PW1[o];
    }

    // ---- phase 1: gather z-fragment in registers ----
    union { bf16x8 v; unsigned short u[8]; } AH[KC1], AL[KC1];

    if (node < nrows) {
        int lo = node ? offend[node - 1] : 0;
        int hi = offend[node];
        float s[KC1][8];
        #pragma unroll
        for (int kc = 0; kc < KC1; ++kc)
            #pragma unroll
            for (int j = 0; j < 8; ++j) s[kc][j] = 0.f;

        const size_t coff = (size_t)lg * 8;   // channel offset of this thread's slots
        int e = lo;
        for (; e + 1 < hi; e += 2) {
            const uint4* pa = (const uint4*)(Hin + (size_t)csr[e] * NCH + coff);
            const uint4* pb = (const uint4*)(Hin + (size_t)csr[e + 1] * NCH + coff);
            uint4 ra[KC1], rb[KC1];
            #pragma unroll
            for (int kc = 0; kc < KC1; ++kc) { ra[kc] = pa[kc * 4]; rb[kc] = pb[kc * 4]; }
            #pragma unroll
            for (int kc = 0; kc < KC1; ++kc) {
                const __half2* ha = (const __half2*)&ra[kc];
                const __half2* hb = (const __half2*)&rb[kc];
                #pragma unroll
                for (int j = 0; j < 4; ++j) {
                    float2 fa = __half22float2(ha[j]);
                    float2 fb = __half22float2(hb[j]);
                    s[kc][j * 2]     += fa.x + fb.x;
                    s[kc][j * 2 + 1] += fa.y + fb.y;
                }
            }
        }
        if (e < hi) {
            const uint4* pa = (const uint4*)(Hin + (size_t)csr[e] * NCH + coff);
            uint4 ra[KC1];
            #pragma unroll
            for (int kc = 0; kc < KC1; ++kc) ra[kc] = pa[kc * 4];
            #pragma unroll
            for (int kc = 0; kc < KC1; ++kc) {
                const __half2* ha = (const __half2*)&ra[kc];
                #pragma unroll
                for (int j = 0; j < 4; ++j) {
                    float2 fa = __half22float2(ha[j]);
                    s[kc][j * 2]     += fa.x;
                    s[kc][j * 2 + 1] += fa.y;
                }
            }
        }
        float invd = 1.0f / fmaxf((float)(hi - lo), 1.0f);
        float e1 = 1.0f + eps_p[layer];
        const uint4* ps = (const uint4*)(Hin + (size_t)node * NCH + coff);
        #pragma unroll
        for (int kc = 0; kc < KC1; ++kc) {
            uint4 rs = ps[kc * 4];
            const __half2* hs = (const __half2*)&rs;
            #pragma unroll
            for (int j = 0; j < 4; ++j) {
                float2 fs = __half22float2(hs[j]);
                float z0 = e1 * fs.x + s[kc][j * 2] * invd;
                float z1 = e1 * fs.y + s[kc][j * 2 + 1] * invd;
                split_bf16(z0, AH[kc].u[j * 2], AL[kc].u[j * 2]);
                split_bf16(z1, AH[kc].u[j * 2 + 1], AL[kc].u[j * 2 + 1]);
            }
        }
    } else {
        #pragma unroll
        for (int kc = 0; kc < KC1; ++kc) {
            AH[kc].v = (bf16x8){0,0,0,0,0,0,0,0};
            AL[kc].v = (bf16x8){0,0,0,0,0,0,0,0};
        }
    }

    __syncthreads();   // W1 staging visible to all waves

    // ---- GEMM1: T = leaky(Z @ W1 + b1), B-frags from LDS ----
    f32x4 acc[NT1];
    #pragma unroll
    for (int nt = 0; nt < NT1; ++nt) acc[nt] = {0.f, 0.f, 0.f, 0.f};

    #pragma unroll
    for (int kc = 0; kc < KC1; ++kc) {
        #pragma unroll
        for (int nt = 0; nt < NT1; ++nt) {
            const int fb = ((kc * NT1 + nt) * 64 + l) * 8;
            bf16x8 bh = *(const bf16x8*)&Wlds[fb];
            bf16x8 bl = *(const bf16x8*)&Wlds[fb + KC1 * NT1 * 512];
            acc[nt] = __builtin_amdgcn_mfma_f32_16x16x32_bf16(AH[kc].v, bh, acc[nt], 0, 0, 0);
            acc[nt] = __builtin_amdgcn_mfma_f32_16x16x32_bf16(AH[kc].v, bl, acc[nt], 0, 0, 0);
            acc[nt] = __builtin_amdgcn_mfma_f32_16x16x32_bf16(AL[kc].v, bh, acc[nt], 0, 0, 0);
        }
    }

    __syncthreads();   // all waves done reading W1

    // ---- re-stage W2 (hi+lo) over the same LDS buffer ----
    #pragma unroll
    for (int i = 0; i < SW2 / 2048; ++i) {
        int o = i * 2048 + tid * 8;
        *(uint4*)&Wlds[o] = *(const uint4*)&PW2[o];
    }
    __syncthreads();   // W2 staging visible

    // ---- GEMM2 interleaved with epilogue-1 via wave-private scratch ----
    f32x4 acc2[NT2];
    #pragma unroll
    for (int nt = 0; nt < NT2; ++nt) acc2[nt] = {0.f, 0.f, 0.f, 0.f};

    #pragma unroll
    for (int kc = 0; kc < KC2; ++kc) {
        #pragma unroll
        for (int t = 0; t < 2; ++t) {
            int nt = kc * 2 + t;
            float bb = B1[nt * 16 + lr];
            #pragma unroll
            for (int r = 0; r < 4; ++r) {
                float v = acc[nt][r] + bb;
                v = v > 0.f ? v : 0.01f * v;
                sw[(lg * 4 + r) * SS + t * 16 + lr] = v;
            }
        }
        const float* tp = &sw[lr * SS + lg * 8];
        f32x4 v0 = *(const f32x4*)tp;
        f32x4 v1 = *(const f32x4*)(tp + 4);
        union { bf16x8 v; unsigned short u[8]; } H, L;
        #pragma unroll
        for (int i = 0; i < 4; ++i) {
            split_bf16(v0[i], H.u[i], L.u[i]);
            split_bf16(v1[i], H.u[i + 4], L.u[i + 4]);
        }
        bf16x8 ah = H.v, al = L.v;
        #pragma unroll
        for (int nt = 0; nt < NT2; ++nt) {
            const int fb = ((kc * NT2 + nt) * 64 + l) * 8;
            bf16x8 bh = *(const bf16x8*)&Wlds[fb];
            bf16x8 bl = *(const bf16x8*)&Wlds[fb + KC2 * NT2 * 512];
            acc2[nt] = __builtin_amdgcn_mfma_f32_16x16x32_bf16(ah, bh, acc2[nt], 0, 0, 0);
            acc2[nt] = __builtin_amdgcn_mfma_f32_16x16x32_bf16(ah, bl, acc2[nt], 0, 0, 0);
            acc2[nt] = __builtin_amdgcn_mfma_f32_16x16x32_bf16(al, bh, acc2[nt], 0, 0, 0);
        }
    }

    // epilogue 2: bias + leaky -> global
    #pragma unroll
    for (int nt = 0; nt < NT2; ++nt) {
        float bb = B2[nt * 16 + lr];
        #pragma unroll
        for (int r = 0; r < 4; ++r) {
            int row = m0 + lg * 4 + r;
            if (row < nrows) {
                float v = acc2[nt][r] + bb;
                v = v > 0.f ? v : 0.01f * v;
                Out[(size_t)row * N2 + nt * 16 + lr] = (OutT)v;
            }
        }
    }
}

// ---------------- launch ----------------

extern "C" void kernel_launch(void* const* d_in, const int* in_sizes, int n_in,
                              void* d_out, int out_size, void* d_ws, size_t ws_size,
                              hipStream_t stream) {
    const float* x   = (const float*)d_in[0];
    const int*   src = (const int*)d_in[1];
    const int*   dst = (const int*)d_in[2];
    const float* eps = (const float*)d_in[3];
    const float* w1s = (const float*)d_in[4];
    const float* b1s = (const float*)d_in[5];
    const float* w2s = (const float*)d_in[6];
    const float* b2s = (const float*)d_in[7];
    const float* wf1 = (const float*)d_in[8];
    const float* bf1 = (const float*)d_in[9];
    const float* wf2 = (const float*)d_in[10];
    const float* bf2 = (const float*)d_in[11];

    const int N = in_sizes[0] / NCH;   // 100000
    const int E = in_sizes[1];         // 600000

    auto align256 = [](size_t v) { return (v + 255) & ~(size_t)255; };
    char* p = (char*)d_ws;
    int* off = (int*)p;              p += align256((size_t)(N + 1) * 4);
    int* part = (int*)p;             p += align256(1024 * 4);
    int* csr = (int*)p;              p += align256((size_t)E * 4);
    __half* xh = (__half*)p;         p += align256((size_t)N * NCH * 2);
    __half* h0 = (__half*)p;         p += align256((size_t)N * NCH * 2);
    __half* h1 = (__half*)p;         p += align256((size_t)N * NCH * 2);
    unsigned short* pw1 = (unsigned short*)p; p += 3 * 65536;
    unsigned short* pw2 = (unsigned short*)p; p += 3 * 65536;
    unsigned short* pwf1 = (unsigned short*)p; p += 32768;
    unsigned short* pwf2 = (unsigned short*)p;

    // CSR build
    const int nScan = N + 1;
    const int nTiles = (nScan + 2047) / 2048;
    hipMemsetAsync(off, 0, (size_t)nScan * 4, stream);
    gin_deg_kernel<<<(E + 255) / 256, 256, 0, stream>>>(dst, off, E);
    gin_scan1<<<nTiles, 256, 0, stream>>>(off, part, nScan);
    gin_scan2<<<1, 256, 0, stream>>>(part, nTiles);
    gin_scan3<<<nTiles, 256, 0, stream>>>(off, part, nScan);
    gin_fill_kernel<<<(E + 255) / 256, 256, 0, stream>>>(src, dst, off, csr, E);

    // x -> fp16 copy for gathering
    const int n4 = N * NCH / 4;
    gin_f2h_kernel<<<(n4 + 255) / 256, 256, 0, stream>>>(x, xh, n4);

    // pack weights
    for (int layer = 0; layer < 3; ++layer) {
        gin_pack_kernel<<<128, 256, 0, stream>>>(w1s + (size_t)layer * 128 * 128, 128, 128,
                                                 (unsigned short*)((char*)pw1 + (size_t)layer * 65536));
        gin_pack_kernel<<<128, 256, 0, stream>>>(w2s + (size_t)layer * 128 * 128, 128, 128,
                                                 (unsigned short*)((char*)pw2 + (size_t)layer * 65536));
    }
    gin_pack_kernel<<<64, 256, 0, stream>>>(wf1, 128, 64, pwf1);
    gin_pack_kernel<<<32, 256, 0, stream>>>(wf2, 64, 64, pwf2);

    const int grid = (N + 63) / 64;

    // layer 0: xh -> h0
    gin_fused<128, 128, __half><<<grid, 256, 0, stream>>>(
        xh, off, csr, eps, 0, pw1, b1s, pw2, b2s, h0, N);
    // layer 1: h0 -> h1
    gin_fused<128, 128, __half><<<grid, 256, 0, stream>>>(
        h0, off, csr, eps, 1,
        (unsigned short*)((char*)pw1 + 65536), b1s + 128,
        (unsigned short*)((char*)pw2 + 65536), b2s + 128, h1, N);
    // layer 2: h1 -> h0
    gin_fused<128, 128, __half><<<grid, 256, 0, stream>>>(
        h1, off, csr, eps, 2,
        (unsigned short*)((char*)pw1 + 2 * 65536), b1s + 256,
        (unsigned short*)((char*)pw2 + 2 * 65536), b2s + 256, h0, N);
    // final layer: h0 -> d_out (128 -> 64 -> 64, f32)
    gin_fused<64, 64, float><<<grid, 256, 0, stream>>>(
        h0, off, csr, eps, 3, pwf1, bf1, pwf2, bf2, (float*)d_out, N);
}